// Round 4
// baseline (519.243 us; speedup 1.0000x reference)
//
#include <hip/hip_runtime.h>
#include <cfloat>
#include <cstdint>

#define NROWS 262144
#define KCB 512
#define DD 64

// numpy pairwise_sum for n=64 (8-accumulator pattern), bit-exact, no contraction
__device__ __forceinline__ float np_pairwise64_sq(const float* a) {
  float r[8];
#pragma unroll
  for (int j = 0; j < 8; ++j) r[j] = __fmul_rn(a[j], a[j]);
#pragma unroll
  for (int i = 8; i < 64; i += 8) {
#pragma unroll
    for (int j = 0; j < 8; ++j) r[j] = __fadd_rn(r[j], __fmul_rn(a[i + j], a[i + j]));
  }
  return __fadd_rn(__fadd_rn(__fadd_rn(r[0], r[1]), __fadd_rn(r[2], r[3])),
                   __fadd_rn(__fadd_rn(r[4], r[5]), __fadd_rn(r[6], r[7])));
}

// ---------------------------------------- w2[k] = np.sum(w*w, axis=1) bit-exact
__global__ __launch_bounds__(512) void w2_kernel(const float* __restrict__ w,
                                                 float* __restrict__ w2) {
  int k = threadIdx.x;
  float wr[64];
  const float4* w4 = (const float4*)(w + (size_t)k * DD);
#pragma unroll
  for (int q = 0; q < 16; ++q) {
    float4 v = w4[q];
    wr[4 * q + 0] = v.x; wr[4 * q + 1] = v.y;
    wr[4 * q + 2] = v.z; wr[4 * q + 3] = v.w;
  }
  w2[k] = np_pairwise64_sq(wr);
}

// ------- main: np-fp32-bit-exact dist + argmin(first index) + z_q + counts
__global__ __launch_bounds__(256, 4) void vq_main(const float* __restrict__ x,
                                                  const float* __restrict__ w,
                                                  const float* __restrict__ w2,
                                                  float* __restrict__ zq,
                                                  int* __restrict__ idx,
                                                  int* __restrict__ counts) {
  __shared__ int ilds[256];
  __shared__ int lc[KCB];
  const int tid = threadIdx.x;
  const int n = blockIdx.x * 256 + tid;
  for (int i = tid; i < KCB; i += 256) lc[i] = 0;

  // x row -> 64 VGPRs
  float xr[64];
  const float4* x4 = (const float4*)(x + (size_t)n * DD);
#pragma unroll
  for (int q = 0; q < 16; ++q) {
    float4 v = x4[q];
    xr[4 * q + 0] = v.x; xr[4 * q + 1] = v.y;
    xr[4 * q + 2] = v.z; xr[4 * q + 3] = v.w;
  }
  // x2[n] exactly as np.sum(x*x, axis=1)
  const float x2n = np_pairwise64_sq(xr);

  const float4* w4 = (const float4*)w;
  float bestd = FLT_MAX;
  int besti = 0;
  for (int kt = 0; kt < KCB; kt += 4) {
    // t = x @ w.T : BLAS sgemm = strict sequential FMA over j per element
    float a0 = 0.f, a1 = 0.f, a2 = 0.f, a3 = 0.f;
#pragma unroll
    for (int q = 0; q < 16; ++q) {
      float4 w0 = w4[(kt + 0) * 16 + q];
      float4 w1 = w4[(kt + 1) * 16 + q];
      float4 w2v = w4[(kt + 2) * 16 + q];
      float4 w3v = w4[(kt + 3) * 16 + q];
      float x0 = xr[4 * q + 0], x1 = xr[4 * q + 1];
      float x2v = xr[4 * q + 2], x3 = xr[4 * q + 3];
      a0 = fmaf(x0, w0.x, a0); a0 = fmaf(x1, w0.y, a0);
      a0 = fmaf(x2v, w0.z, a0); a0 = fmaf(x3, w0.w, a0);
      a1 = fmaf(x0, w1.x, a1); a1 = fmaf(x1, w1.y, a1);
      a1 = fmaf(x2v, w1.z, a1); a1 = fmaf(x3, w1.w, a1);
      a2 = fmaf(x0, w2v.x, a2); a2 = fmaf(x1, w2v.y, a2);
      a2 = fmaf(x2v, w2v.z, a2); a2 = fmaf(x3, w2v.w, a2);
      a3 = fmaf(x0, w3v.x, a3); a3 = fmaf(x1, w3v.y, a3);
      a3 = fmaf(x2v, w3v.z, a3); a3 = fmaf(x3, w3v.w, a3);
    }
    // dist = fl(fl(x2 - 2t) + w2)  (2t exact; np elementwise order)
    const float* w2p = w2 + kt;
    float d0 = __fadd_rn(__fsub_rn(x2n, 2.0f * a0), w2p[0]);
    float d1 = __fadd_rn(__fsub_rn(x2n, 2.0f * a1), w2p[1]);
    float d2 = __fadd_rn(__fsub_rn(x2n, 2.0f * a2), w2p[2]);
    float d3 = __fadd_rn(__fsub_rn(x2n, 2.0f * a3), w2p[3]);
    // np.argmin: first occurrence of min == strict < in ascending k
    if (d0 < bestd) { bestd = d0; besti = kt + 0; }
    if (d1 < bestd) { bestd = d1; besti = kt + 1; }
    if (d2 < bestd) { bestd = d2; besti = kt + 2; }
    if (d3 < bestd) { bestd = d3; besti = kt + 3; }
  }
  idx[n] = besti;
  ilds[tid] = besti;
  __syncthreads();
  atomicAdd(&lc[besti], 1);

  // cooperative coalesced z_q gather: 256 rows x 16 float4
  const size_t zbase = (size_t)blockIdx.x * 256 * 16;
  float4* zq4 = (float4*)zq;
#pragma unroll
  for (int it = 0; it < 16; ++it) {
    int e = it * 256 + tid;
    int row = e >> 4;
    int col = e & 15;
    int kk = ilds[row];
    zq4[zbase + e] = w4[kk * 16 + col];
  }
  __syncthreads();
  for (int i = tid; i < KCB; i += 256) {
    int c = lc[i];
    if (c) atomicAdd(&counts[i], c);
  }
}

// --------------------------- scatter: per-block LDS partial sums (two d-halves)
__global__ __launch_bounds__(256) void scatter_partial(const float* __restrict__ x,
                                                       const int* __restrict__ idx,
                                                       float* __restrict__ psums) {
  __shared__ float ls[KCB * 32];  // 64 KiB
  const int tid = threadIdx.x;
  const int bid = blockIdx.x;               // 0..255
  const int rows_per_block = NROWS / 256;   // 1024
  const int r0 = bid * rows_per_block;
  const int rsub = tid >> 3;                // 0..31
  const int dq = tid & 7;                   // float4 quad within 32-col half
  for (int half = 0; half < 2; ++half) {
    for (int i = tid; i < KCB * 32; i += 256) ls[i] = 0.f;
    __syncthreads();
    for (int rr = 0; rr < rows_per_block; rr += 32) {
      int row = r0 + rr + rsub;
      int k = idx[row];
      float4 v = *(const float4*)(x + (size_t)row * DD + half * 32 + dq * 4);
      float* b = ls + k * 32;
      atomicAdd(&b[((dq * 4 + 0) + k) & 31], v.x);
      atomicAdd(&b[((dq * 4 + 1) + k) & 31], v.y);
      atomicAdd(&b[((dq * 4 + 2) + k) & 31], v.z);
      atomicAdd(&b[((dq * 4 + 3) + k) & 31], v.w);
    }
    __syncthreads();
    for (int i = tid; i < KCB * 32; i += 256) {
      int k = i >> 5, dl = i & 31;
      psums[(size_t)bid * (KCB * DD) + k * DD + half * 32 + dl] =
          ls[k * 32 + ((dl + k) & 31)];
    }
    __syncthreads();
  }
}

// ----------------------------- reduce partials -> mean -> dict_grad
__global__ __launch_bounds__(256) void reduce_dg(const float* __restrict__ psums,
                                                 const int* __restrict__ counts,
                                                 const float* __restrict__ w,
                                                 float* __restrict__ dg) {
  int e = blockIdx.x * 256 + threadIdx.x;  // < KCB*DD
  int k = e >> 6;
  float s = 0.f;
  for (int p = 0; p < 256; ++p) s = __fadd_rn(s, psums[(size_t)p * (KCB * DD) + e]);
  int c = counts[k];
  float mean = s / fmaxf((float)c, 1.f);
  dg[e] = (c > 0) ? (-2.0f * __fsub_rn(mean, w[e])) : 0.f;
}

// ----------------------------- fallback path (small ws): global atomics
__global__ __launch_bounds__(256) void scatter_atomic(const float* __restrict__ x,
                                                      const int* __restrict__ idx,
                                                      float* __restrict__ sums) {
  int n = blockIdx.x * 256 + threadIdx.x;
  int k = idx[n];
  const float4* x4 = (const float4*)(x + (size_t)n * DD);
  float* s = sums + k * DD;
#pragma unroll
  for (int q = 0; q < 16; ++q) {
    float4 v = x4[q];
    atomicAdd(&s[4 * q + 0], v.x); atomicAdd(&s[4 * q + 1], v.y);
    atomicAdd(&s[4 * q + 2], v.z); atomicAdd(&s[4 * q + 3], v.w);
  }
}

__global__ __launch_bounds__(256) void dg_from_sums(const float* __restrict__ sums,
                                                    const int* __restrict__ counts,
                                                    const float* __restrict__ w,
                                                    float* __restrict__ dg) {
  int e = blockIdx.x * 256 + threadIdx.x;  // < KCB*DD
  int k = e >> 6;
  int c = counts[k];
  float mean = sums[e] / fmaxf((float)c, 1.f);
  dg[e] = (c > 0) ? (-2.0f * __fsub_rn(mean, w[e])) : 0.f;
}

extern "C" void kernel_launch(void* const* d_in, const int* in_sizes, int n_in,
                              void* d_out, int out_size, void* d_ws, size_t ws_size,
                              hipStream_t stream) {
  const float* x = (const float*)d_in[0];
  const float* w = (const float*)d_in[1];
  float* zq = (float*)d_out;
  float* dg = (float*)d_out + (size_t)NROWS * DD;

  char* ws = (char*)d_ws;
  int* idx = (int*)ws;                              // 1 MiB
  float* w2p = (float*)(ws + (1 << 20));            // 2 KiB (4 KiB pad)
  int* counts = (int*)(ws + (1 << 20) + 4096);      // 2 KiB (4 KiB pad)
  float* psums = (float*)(ws + (1 << 20) + 8192);   // 256*512*64*4 = 32 MiB
  const size_t need_partial =
      (size_t)(1 << 20) + 8192 + (size_t)256 * KCB * DD * sizeof(float);

  hipMemsetAsync(counts, 0, KCB * sizeof(int), stream);
  w2_kernel<<<1, 512, 0, stream>>>(w, w2p);
  vq_main<<<NROWS / 256, 256, 0, stream>>>(x, w, w2p, zq, idx, counts);

  if (ws_size >= need_partial) {
    scatter_partial<<<256, 256, 0, stream>>>(x, idx, psums);
    reduce_dg<<<KCB * DD / 256, 256, 0, stream>>>(psums, counts, w, dg);
  } else {
    float* sums = psums;  // 128 KiB, fits in the smaller footprint too
    hipMemsetAsync(sums, 0, KCB * DD * sizeof(float), stream);
    scatter_atomic<<<NROWS / 256, 256, 0, stream>>>(x, idx, sums);
    dg_from_sums<<<KCB * DD / 256, 256, 0, stream>>>(sums, counts, w, dg);
  }
}